// Round 9
// baseline (905.865 us; speedup 1.0000x reference)
//
#include <hip/hip_runtime.h>
#include <hip/hip_bf16.h>

typedef unsigned short u16;
typedef unsigned int   u32;
typedef __bf16 bf16x8 __attribute__((ext_vector_type(8)));
typedef float  f32x4  __attribute__((ext_vector_type(4)));
typedef float  f32x2  __attribute__((ext_vector_type(2)));

#define M_TOK 100352
#define M_HALF 50176
#define DIMC  192
#define HIDC  768
#define SCALE_F 0.17677669529663688f

__device__ __forceinline__ float b2f(u16 u) {
    u32 x = ((u32)u) << 16; float f; __builtin_memcpy(&f, &x, 4); return f;
}
__device__ __forceinline__ u16 f2b(float f) {
    u32 x; __builtin_memcpy(&x, &f, 4);
    x = x + 0x7FFFu + ((x >> 16) & 1u);
    return (u16)(x >> 16);
}
__device__ __forceinline__ float lo2f(u32 w) {
    u32 x = w << 16; float f; __builtin_memcpy(&f, &x, 4); return f;
}
__device__ __forceinline__ float hi2f(u32 w) {
    u32 x = w & 0xFFFF0000u; float f; __builtin_memcpy(&f, &x, 4); return f;
}
__device__ __forceinline__ void g2l16(const u16* g, u16* l) {
    __builtin_amdgcn_global_load_lds(
        (const __attribute__((address_space(1))) u32*)g,
        (__attribute__((address_space(3))) u32*)l, 16, 0, 0);
}

// ---------------------------------------------------------------------------
// Weight prep (unchanged)
// ---------------------------------------------------------------------------
__global__ __launch_bounds__(256) void prep_weights(
    const float* __restrict__ qkv_w, const float* __restrict__ proj_w,
    const float* __restrict__ fc1_w, const float* __restrict__ fc2_w,
    const float* __restrict__ dw_w,
    u16* __restrict__ qkvt, u16* __restrict__ projt, u16* __restrict__ fc1t,
    u16* __restrict__ fc2t, float* __restrict__ dwtf)
{
    int id = blockIdx.x * 256 + threadIdx.x;
    if (id < 110592)      { int n = id / 192, k = id % 192;                 qkvt[id] = f2b(qkv_w[k * 576 + n]); }
    else if (id < 147456) { int e = id - 110592, n = e / 192, k = e % 192;  projt[e] = f2b(proj_w[k * 192 + n]); }
    else if (id < 294912) { int e = id - 147456, n = e / 192, k = e % 192;  fc1t[e]  = f2b(fc1_w[k * 768 + n]); }
    else if (id < 442368) { int e = id - 294912, n = e / 768, k = e % 768;  fc2t[e]  = f2b(fc2_w[k * 192 + n]); }
    else if (id < 463104) { int e = id - 442368, t = e / 768, c = e % 768;  dwtf[e]  = dw_w[c * 27 + t]; }
}

// ---------------------------------------------------------------------------
// Relative-position bias matrix, PADDED: bmat[head][112][112] f32 (unchanged)
// ---------------------------------------------------------------------------
__global__ __launch_bounds__(256) void biasmat_kernel(
    const float* __restrict__ btab, float* __restrict__ bmat)
{
    int id = blockIdx.x * 256 + threadIdx.x;
    if (id >= 6 * 112 * 112) return;
    int h = id / 12544, rem = id % 12544, i = rem / 112, j = rem % 112;
    float v;
    if (j >= 98)      v = -1e30f;
    else if (i >= 98) v = 0.0f;
    else {
        int di = i / 49, hi = (i / 7) % 7, wi = i % 7;
        int dj = j / 49, hj = (j / 7) % 7, wj = j % 7;
        int idx = (di - dj + 1) * 169 + (hi - hj + 6) * 13 + (wi - wj + 6);
        v = btab[idx * 6 + h];
    }
    bmat[id] = v;
}

// ---------------------------------------------------------------------------
// LayerNorm (unchanged)
// ---------------------------------------------------------------------------
template<bool PERM, bool BF_IN>
__global__ __launch_bounds__(256) void ln_kernel(
    const void* __restrict__ xin, const float* __restrict__ g,
    const float* __restrict__ bb, u16* __restrict__ out)
{
    int row  = blockIdx.x * 4 + (threadIdx.x >> 6);
    int lane = threadIdx.x & 63;
    float v0, v1, v2;
    if (BF_IN) {
        const u16* xr = (const u16*)xin + (size_t)row * DIMC;
        v0 = b2f(xr[lane]); v1 = b2f(xr[lane + 64]); v2 = b2f(xr[lane + 128]);
    } else {
        const float* xr = (const float*)xin + (size_t)row * DIMC;
        v0 = xr[lane]; v1 = xr[lane + 64]; v2 = xr[lane + 128];
    }
    float s  = v0 + v1 + v2;
    float s2 = v0 * v0 + v1 * v1 + v2 * v2;
    #pragma unroll
    for (int m = 1; m < 64; m <<= 1) { s += __shfl_xor(s, m); s2 += __shfl_xor(s2, m); }
    float mu = s * (1.0f / 192.0f);
    float rs = rsqrtf(s2 * (1.0f / 192.0f) - mu * mu + 1e-5f);
    size_t ob;
    if (PERM) {
        int b = row / 50176, r = row % 50176;
        int d = r / 3136, r2 = r % 3136, h = r2 / 56, w = r2 % 56;
        int widx = ((b * 8 + (d >> 1)) * 8 + h / 7) * 8 + w / 7;
        int tok  = (d & 1) * 49 + (h % 7) * 7 + (w % 7);
        ob = ((size_t)widx * 98 + tok) * DIMC;
    } else {
        ob = (size_t)row * DIMC;
    }
    out[ob + lane]       = f2b((v0 - mu) * rs * g[lane]       + bb[lane]);
    out[ob + lane + 64]  = f2b((v1 - mu) * rs * g[lane + 64]  + bb[lane + 64]);
    out[ob + lane + 128] = f2b((v2 - mu) * rs * g[lane + 128] + bb[lane + 128]);
}

// ---------------------------------------------------------------------------
// bf16 MFMA GEMM, BK=64: LDS layout [kk][rows][32] so ds_reads keep the
// proven 64B-row 2-way-free pattern; staging stays global_load_lds-linear
// (6 calls, remapped pass bases). Half the barrier drains of BK=32.
// ---------------------------------------------------------------------------
template<int EPI>
__global__ __launch_bounds__(256) void gemm_bt(
    const u16* __restrict__ A, const u16* __restrict__ Bt,
    const float* __restrict__ bias, int K, int N, int NBN,
    u16* __restrict__ outb, const float* __restrict__ xres,
    u16* __restrict__ x2b, float* __restrict__ outf, int mofs)
{
    __shared__ __align__(16) u16 Alds[2 * 128 * 32];   // 16 KB
    __shared__ __align__(16) u16 Blds[2 * 64 * 32];    // 8 KB
    int bid = blockIdx.x;
    int cpx = gridDim.x >> 3;
    int swz = (bid & 7) * cpx + (bid >> 3);
    int m0 = (swz / NBN) * 128;
    int n0 = (swz % NBN) * 64;
    int t  = threadIdx.x;
    int lane = t & 63, wid = t >> 6;
    int wm = wid >> 1, wn = wid & 1;
    int lrow = lane & 15, lko = (lane >> 4) * 8;
    int sr = t >> 2, sc = (t & 3) * 8;        // staging: 4 threads/row of 32
    const u16* Ag = A  + (size_t)(m0 + sr) * K + sc;
    const u16* Bg = Bt + (size_t)(n0 + sr) * K + sc;
    u16* lA = Alds + t * 8;
    u16* lB = Blds + t * 8;
    f32x4 acc[4][2] = {};
    for (int kt = 0; kt < K; kt += 64) {
        __syncthreads();
        g2l16(Ag + kt,                    lA);            // kk0, rows 0-63
        g2l16(Ag + (size_t)64 * K + kt,   lA + 2048);     // kk0, rows 64-127
        g2l16(Ag + kt + 32,               lA + 4096);     // kk1, rows 0-63
        g2l16(Ag + (size_t)64 * K + kt + 32, lA + 6144);  // kk1, rows 64-127
        g2l16(Bg + kt,      lB);                          // kk0
        g2l16(Bg + kt + 32, lB + 2048);                   // kk1
        __syncthreads();
        #pragma unroll
        for (int kk = 0; kk < 2; ++kk) {
            bf16x8 af[4], bfr[2];
            #pragma unroll
            for (int mi = 0; mi < 4; mi++)
                af[mi] = *(const bf16x8*)&Alds[kk * 4096 + (wm * 64 + mi * 16 + lrow) * 32 + lko];
            #pragma unroll
            for (int ni = 0; ni < 2; ni++)
                bfr[ni] = *(const bf16x8*)&Blds[kk * 2048 + (wn * 32 + ni * 16 + lrow) * 32 + lko];
            #pragma unroll
            for (int mi = 0; mi < 4; mi++)
                #pragma unroll
                for (int ni = 0; ni < 2; ni++)
                    acc[mi][ni] = __builtin_amdgcn_mfma_f32_16x16x32_bf16(af[mi], bfr[ni], acc[mi][ni], 0, 0, 0);
        }
    }
    int r0 = (lane >> 4) * 4, cl = lane & 15;
    #pragma unroll
    for (int ni = 0; ni < 2; ni++) {
        int col = n0 + wn * 32 + ni * 16 + cl;
        float bv = bias[col];
        #pragma unroll
        for (int mi = 0; mi < 4; mi++) {
            #pragma unroll
            for (int r = 0; r < 4; r++) {
                int row = m0 + wm * 64 + mi * 16 + r0 + r;
                float v = acc[mi][ni][r] + bv;
                if (EPI == 0) {
                    outb[(size_t)row * N + col] = f2b(v);
                } else if (EPI == 1) {
                    int widx = row / 98, tok = row % 98;
                    int b = widx >> 9, rem = widx & 511;
                    int bd = rem >> 6, bh = (rem >> 3) & 7, bw = rem & 7;
                    int td = tok / 49, rr = tok % 49, th = rr / 7, tw = rr % 7;
                    int d = bd * 2 + td, h = bh * 7 + th, w = bw * 7 + tw;
                    size_t gg = ((size_t)b * 50176 + (d * 56 + h) * 56 + w) * (size_t)N + col;
                    x2b[gg] = f2b(xres[gg] + 0.5f * v);
                } else {
                    size_t gg = (size_t)(row + mofs) * N + col;
                    outf[gg] = b2f(x2b[gg]) + 0.5f * v;
                }
            }
        }
    }
}

// ---------------------------------------------------------------------------
// MFMA window attention (unchanged)
// ---------------------------------------------------------------------------
__global__ __launch_bounds__(64) void attn_mfma_kernel(
    const u16* __restrict__ qkv, const float* __restrict__ bmat,
    u16* __restrict__ outb)
{
    __shared__ __align__(16) u16 Klds[112 * 40];
    __shared__ __align__(16) u16 Vt[32 * 136];
    __shared__ __align__(16) u16 Plds[16 * 136];
    int widx = blockIdx.x, head = blockIdx.y;
    int l = threadIdx.x;
    int c = l & 15, g = l >> 4;
    size_t wbase = (size_t)widx * (98 * 576) + head * 32;

    for (int e = l; e < 448; e += 64) {
        int rr = e >> 2, seg = (e & 3) * 8;
        uint4 kr = {0, 0, 0, 0}, vr = {0, 0, 0, 0};
        if (rr < 98) {
            kr = *(const uint4*)(qkv + wbase + (size_t)rr * 576 + 192 + seg);
            vr = *(const uint4*)(qkv + wbase + (size_t)rr * 576 + 384 + seg);
        }
        *(uint4*)&Klds[rr * 40 + seg] = kr;
        int sw = ((seg >> 3) & 3) << 4;
        int pc = rr ^ sw;
        const u16* vp = (const u16*)&vr;
        #pragma unroll
        for (int u = 0; u < 8; u++)
            Vt[(seg + u) * 136 + pc] = vp[u];
    }
    {
        int d = l >> 1, half = l & 1;
        int sw = ((d >> 3) & 3) << 4;
        uint4 z = {0, 0, 0, 0};
        *(uint4*)&Vt[d * 136 + ((112 + 8 * half) ^ sw)] = z;
        if (l < 32) {
            int i = l >> 1; half = l & 1;
            int swp = ((i >> 2) & 3) << 4;
            *(uint4*)&Plds[i * 136 + ((112 + 8 * half) ^ swp)] = z;
        }
    }

    for (int it = 0; it < 7; ++it) {
        int qtok = 16 * it + c; if (qtok > 97) qtok = 97;
        bf16x8 qf = *(const bf16x8*)(qkv + wbase + (size_t)qtok * 576 + g * 8);
        f32x4 s[7];
        f32x4 z = {};
        #pragma unroll
        for (int jt = 0; jt < 7; ++jt) {
            bf16x8 kf = *(const bf16x8*)&Klds[(16 * jt + c) * 40 + g * 8];
            s[jt] = __builtin_amdgcn_mfma_f32_16x16x32_bf16(qf, kf, z, 0, 0, 0);
        }
        const float* bb = bmat + ((size_t)head * 112 + 16 * it + 4 * g) * 112 + c;
        float sm[4];
        #pragma unroll
        for (int r = 0; r < 4; ++r) {
            float m = -1e30f;
            #pragma unroll
            for (int jt = 0; jt < 7; ++jt) {
                float v = s[jt][r] * SCALE_F + bb[r * 112 + 16 * jt];
                s[jt][r] = v;
                m = fmaxf(m, v);
            }
            m = fmaxf(m, __shfl_xor(m, 1)); m = fmaxf(m, __shfl_xor(m, 2));
            m = fmaxf(m, __shfl_xor(m, 4)); m = fmaxf(m, __shfl_xor(m, 8));
            float su = 0.f;
            #pragma unroll
            for (int jt = 0; jt < 7; ++jt) {
                float p = __expf(s[jt][r] - m);
                s[jt][r] = p;
                su += p;
            }
            su += __shfl_xor(su, 1); su += __shfl_xor(su, 2);
            su += __shfl_xor(su, 4); su += __shfl_xor(su, 8);
            sm[r] = su;
        }
        #pragma unroll
        for (int r = 0; r < 4; ++r) {
            int prow = 4 * g + r;
            int swp = ((prow >> 2) & 3) << 4;
            #pragma unroll
            for (int jt = 0; jt < 7; ++jt)
                Plds[prow * 136 + ((16 * jt + c) ^ swp)] = f2b(s[jt][r]);
        }
        bf16x8 pa[4];
        int swr = ((c >> 2) & 3) << 4;
        #pragma unroll
        for (int ks = 0; ks < 4; ++ks)
            pa[ks] = *(const bf16x8*)&Plds[c * 136 + ((32 * ks + 8 * g) ^ swr)];
        #pragma unroll
        for (int dt = 0; dt < 2; ++dt) {
            f32x4 o = {};
            int vrow = 16 * dt + c;
            int swv = ((vrow >> 3) & 3) << 4;
            #pragma unroll
            for (int ks = 0; ks < 4; ++ks) {
                bf16x8 vb = *(const bf16x8*)&Vt[vrow * 136 + ((32 * ks + 8 * g) ^ swv)];
                o = __builtin_amdgcn_mfma_f32_16x16x32_bf16(pa[ks], vb, o, 0, 0, 0);
            }
            #pragma unroll
            for (int r = 0; r < 4; ++r) {
                int row = 16 * it + 4 * g + r;
                if (row < 98)
                    outb[((size_t)widx * 98 + row) * DIMC + head * 32 + 16 * dt + c]
                        = f2b(o[r] / sm[r]);
            }
        }
    }
}

// ---------------------------------------------------------------------------
// Depthwise conv + GELU, INTERIOR: d in [1,14], h in [1,54], w in [4,52).
// No bounds checks; all 9 row bases are compile-time offsets from one pointer.
// Thread = 4 w-outputs x 4 channels. 73% of the volume.
// ---------------------------------------------------------------------------
__global__ __launch_bounds__(256, 8) void dwconv_gelu_int(
    const u16* __restrict__ hid, const float* __restrict__ dwtf,
    const float* __restrict__ dwb, u16* __restrict__ outb)
{
    int bid = blockIdx.x;
    // bijective XCD swizzle for nwg=6804 (q=850, r=4)
    int xcd = bid & 7, lin = bid >> 3;
    int swz = (xcd < 4 ? xcd * 851 : 3404 + (xcd - 4) * 850) + lin;
    int gid = swz * 256 + threadIdx.x;
    int cg = gid % 192;
    int iu = gid / 192;
    int d  = iu % 14 + 1;
    int r  = iu / 14;
    int wg = r % 12;
    int h  = r / 12 + 1;
    int w0 = wg * 4 + 4;
    int c0 = cg * 4;

    f32x2 acc[4][2];
    {
        float4 bv = *(const float4*)(dwb + c0);
        #pragma unroll
        for (int wi = 0; wi < 4; ++wi) {
            acc[wi][0] = f32x2{bv.x, bv.y};
            acc[wi][1] = f32x2{bv.z, bv.w};
        }
    }

    const u16* rp0 = hid + (((size_t)(d - 1) * 56 + (h - 1)) * 56 + (w0 - 1)) * HIDC + c0;
    const float* wb0 = dwtf + c0;
    #pragma unroll
    for (int iz = 0; iz < 3; ++iz) {
        #pragma unroll
        for (int iy = 0; iy < 3; ++iy) {
            const u16* rp = rp0 + (size_t)(iz * 3136 + iy * 56) * HIDC;
            uint2 raw[6];
            #pragma unroll
            for (int ix = 0; ix < 6; ++ix)
                raw[ix] = *(const uint2*)(rp + (size_t)ix * HIDC);
            const float* wrow = wb0 + (size_t)(iz * 9 + iy * 3) * HIDC;
            float4 wv0 = *(const float4*)(wrow);
            float4 wv1 = *(const float4*)(wrow + HIDC);
            float4 wv2 = *(const float4*)(wrow + 2 * HIDC);
            f32x2 wp[3][2] = {
                { f32x2{wv0.x, wv0.y}, f32x2{wv0.z, wv0.w} },
                { f32x2{wv1.x, wv1.y}, f32x2{wv1.z, wv1.w} },
                { f32x2{wv2.x, wv2.y}, f32x2{wv2.z, wv2.w} } };
            #pragma unroll
            for (int p = 0; p < 6; ++p) {
                f32x2 i0 = f32x2{lo2f(raw[p].x), hi2f(raw[p].x)};
                f32x2 i1 = f32x2{lo2f(raw[p].y), hi2f(raw[p].y)};
                #pragma unroll
                for (int dx = 0; dx < 3; ++dx) {
                    if (dx > p || dx < p - 3) continue;
                    acc[p - dx][0] += i0 * wp[dx][0];
                    acc[p - dx][1] += i1 * wp[dx][1];
                }
            }
        }
    }

    size_t tok0 = (size_t)(d * 56 + h) * 56 + w0;
    #pragma unroll
    for (int wi = 0; wi < 4; ++wi) {
        u16 res[4];
        #pragma unroll
        for (int pr = 0; pr < 2; ++pr)
            #pragma unroll
            for (int u = 0; u < 2; ++u) {
                float a = acc[wi][pr][u];
                float tt = a * (1.5957691216f + 0.0713548162f * a * a);
                res[pr * 2 + u] = f2b(a / (1.0f + __expf(-tt)));
            }
        uint2 ov;
        ov.x = (u32)res[0] | ((u32)res[1] << 16);
        ov.y = (u32)res[2] | ((u32)res[3] << 16);
        *(uint2*)(outb + (tok0 + wi) * HIDC + c0) = ov;
    }
}

// ---------------------------------------------------------------------------
// Depthwise conv + GELU, EDGE shell (3472 units): checked version.
//   u < 1568:        d in {0,15}, all h, all wg
//   1568 <= u <1960: h in {0,55}, d in [1,14]
//   else:            wg in {0,13}, d in [1,14], h in [1,54]
// ---------------------------------------------------------------------------
__global__ __launch_bounds__(256, 8) void dwconv_gelu_edge(
    const u16* __restrict__ hid, const float* __restrict__ dwtf,
    const float* __restrict__ dwb, u16* __restrict__ outb)
{
    int gid = blockIdx.x * 256 + threadIdx.x;
    int cg = gid % 192;
    int u  = gid / 192;
    int d, h, wg;
    if (u < 1568)      { d = (u < 784) ? 0 : 15; int rr = u % 784; h = rr / 14; wg = rr % 14; }
    else if (u < 1960) { int rr = u - 1568; h = (rr < 196) ? 0 : 55; rr %= 196; d = 1 + rr / 14; wg = rr % 14; }
    else               { int rr = u - 1960; wg = (rr < 756) ? 0 : 13; rr %= 756; d = 1 + rr / 54; h = 1 + rr % 54; }
    int w0 = wg * 4;
    int c0 = cg * 4;

    f32x2 acc[4][2];
    {
        float4 bv = *(const float4*)(dwb + c0);
        #pragma unroll
        for (int wi = 0; wi < 4; ++wi) {
            acc[wi][0] = f32x2{bv.x, bv.y};
            acc[wi][1] = f32x2{bv.z, bv.w};
        }
    }

    #pragma unroll
    for (int iz = 0; iz < 3; ++iz) {
        int zz = d - 1 + iz;
        if ((unsigned)zz >= 16u) continue;
        #pragma unroll
        for (int iy = 0; iy < 3; ++iy) {
            int yy = h - 1 + iy;
            if ((unsigned)yy >= 56u) continue;
            uint2 raw[6];
            const u16* rp = hid + ((size_t)(zz * 56 + yy) * 56 + w0 - 1) * HIDC + c0;
            #pragma unroll
            for (int ix = 0; ix < 6; ++ix) {
                uint2 iv = {0, 0};
                if ((unsigned)(w0 - 1 + ix) < 56u)
                    iv = *(const uint2*)(rp + (size_t)ix * HIDC);
                raw[ix] = iv;
            }
            const float* wrow = dwtf + (size_t)(iz * 9 + iy * 3) * HIDC + c0;
            float4 wv0 = *(const float4*)(wrow);
            float4 wv1 = *(const float4*)(wrow + HIDC);
            float4 wv2 = *(const float4*)(wrow + 2 * HIDC);
            f32x2 wp[3][2] = {
                { f32x2{wv0.x, wv0.y}, f32x2{wv0.z, wv0.w} },
                { f32x2{wv1.x, wv1.y}, f32x2{wv1.z, wv1.w} },
                { f32x2{wv2.x, wv2.y}, f32x2{wv2.z, wv2.w} } };
            #pragma unroll
            for (int p = 0; p < 6; ++p) {
                f32x2 i0 = f32x2{lo2f(raw[p].x), hi2f(raw[p].x)};
                f32x2 i1 = f32x2{lo2f(raw[p].y), hi2f(raw[p].y)};
                #pragma unroll
                for (int dx = 0; dx < 3; ++dx) {
                    if (dx > p || dx < p - 3) continue;
                    acc[p - dx][0] += i0 * wp[dx][0];
                    acc[p - dx][1] += i1 * wp[dx][1];
                }
            }
        }
    }

    size_t tok0 = (size_t)(d * 56 + h) * 56 + w0;
    #pragma unroll
    for (int wi = 0; wi < 4; ++wi) {
        u16 res[4];
        #pragma unroll
        for (int pr = 0; pr < 2; ++pr)
            #pragma unroll
            for (int u2 = 0; u2 < 2; ++u2) {
                float a = acc[wi][pr][u2];
                float tt = a * (1.5957691216f + 0.0713548162f * a * a);
                res[pr * 2 + u2] = f2b(a / (1.0f + __expf(-tt)));
            }
        uint2 ov;
        ov.x = (u32)res[0] | ((u32)res[1] << 16);
        ov.y = (u32)res[2] | ((u32)res[3] << 16);
        *(uint2*)(outb + (tok0 + wi) * HIDC + c0) = ov;
    }
}

// ---------------------------------------------------------------------------
// Orchestration (workspace layout unchanged).
// ---------------------------------------------------------------------------
extern "C" void kernel_launch(void* const* d_in, const int* in_sizes, int n_in,
                              void* d_out, int out_size, void* d_ws, size_t ws_size,
                              hipStream_t stream)
{
    const float* x      = (const float*)d_in[0];
    const float* n1g    = (const float*)d_in[1];
    const float* n1b    = (const float*)d_in[2];
    const float* qkv_w  = (const float*)d_in[3];
    const float* qkv_b  = (const float*)d_in[4];
    const float* btab   = (const float*)d_in[5];
    const float* proj_w = (const float*)d_in[6];
    const float* proj_b = (const float*)d_in[7];
    const float* n2g    = (const float*)d_in[8];
    const float* n2b    = (const float*)d_in[9];
    const float* fc1_w  = (const float*)d_in[10];
    const float* fc1_b  = (const float*)d_in[11];
    const float* dw_w   = (const float*)d_in[12];
    const float* dw_b   = (const float*)d_in[13];
    const float* fc2_w  = (const float*)d_in[14];
    const float* fc2_b  = (const float*)d_in[15];

    char* ws = (char*)d_ws;
    u16*   qkvt  = (u16*)(ws);
    u16*   projt = (u16*)(ws + 221184);
    u16*   fc1t  = (u16*)(ws + 294912);
    u16*   fc2t  = (u16*)(ws + 589824);
    float* dwtf  = (float*)(ws + 884736);
    u16*   r1    = (u16*)(ws + 1160192);
    u16*   qkvb  = (u16*)(ws + 39695360LL);
    u16*   x2b   = (u16*)(ws + 39695360LL);
    u16*   hid_c = (u16*)(ws + 78230528LL);
    float* bmat  = (float*)(ws + 155300864LL);
    u16*   gelu_c= (u16*)(ws + 155300864LL);

    prep_weights<<<dim3(1809), dim3(256), 0, stream>>>(qkv_w, proj_w, fc1_w, fc2_w, dw_w,
                                                       qkvt, projt, fc1t, fc2t, dwtf);
    biasmat_kernel<<<dim3(294), dim3(256), 0, stream>>>(btab, bmat);
    ln_kernel<true, false><<<dim3(25088), dim3(256), 0, stream>>>(x, n1g, n1b, r1);
    gemm_bt<0><<<dim3(7056), dim3(256), 0, stream>>>(r1, qkvt, qkv_b, 192, 576, 9,
                                                     qkvb, nullptr, nullptr, nullptr, 0);
    attn_mfma_kernel<<<dim3(1024, 6), dim3(64), 0, stream>>>(qkvb, bmat, r1);
    gemm_bt<1><<<dim3(2352), dim3(256), 0, stream>>>(r1, projt, proj_b, 192, 192, 3,
                                                     nullptr, x, x2b, nullptr, 0);
    ln_kernel<false, true><<<dim3(25088), dim3(256), 0, stream>>>(x2b, n2g, n2b, r1);
    for (int b = 0; b < 2; b++) {
        const u16* h2c = r1 + (size_t)b * M_HALF * DIMC;
        gemm_bt<0><<<dim3(4704), dim3(256), 0, stream>>>(h2c, fc1t, fc1_b, 192, 768, 12,
                                                         hid_c, nullptr, nullptr, nullptr, 0);
        dwconv_gelu_int<<<dim3(6804), dim3(256), 0, stream>>>(hid_c, dwtf, dw_b, gelu_c);
        dwconv_gelu_edge<<<dim3(2604), dim3(256), 0, stream>>>(hid_c, dwtf, dw_b, gelu_c);
        gemm_bt<2><<<dim3(1176), dim3(256), 0, stream>>>(gelu_c, fc2t, fc2_b, 768, 192, 3,
                                                         nullptr, nullptr, x2b, (float*)d_out,
                                                         b * M_HALF);
    }
}

// Round 10
// 705.669 us; speedup vs baseline: 1.2837x; 1.2837x over previous
//
#include <hip/hip_runtime.h>
#include <hip/hip_bf16.h>

typedef unsigned short u16;
typedef unsigned int   u32;
typedef __bf16 bf16x8 __attribute__((ext_vector_type(8)));
typedef float  f32x4  __attribute__((ext_vector_type(4)));
typedef float  f32x2  __attribute__((ext_vector_type(2)));

#define M_TOK 100352
#define M_HALF 50176
#define DIMC  192
#define HIDC  768
#define SCALE_F 0.17677669529663688f

__device__ __forceinline__ float b2f(u16 u) {
    u32 x = ((u32)u) << 16; float f; __builtin_memcpy(&f, &x, 4); return f;
}
__device__ __forceinline__ u16 f2b(float f) {
    u32 x; __builtin_memcpy(&x, &f, 4);
    x = x + 0x7FFFu + ((x >> 16) & 1u);
    return (u16)(x >> 16);
}
__device__ __forceinline__ float lo2f(u32 w) {
    u32 x = w << 16; float f; __builtin_memcpy(&f, &x, 4); return f;
}
__device__ __forceinline__ float hi2f(u32 w) {
    u32 x = w & 0xFFFF0000u; float f; __builtin_memcpy(&f, &x, 4); return f;
}
__device__ __forceinline__ void g2l16(const u16* g, u16* l) {
    __builtin_amdgcn_global_load_lds(
        (const __attribute__((address_space(1))) u32*)g,
        (__attribute__((address_space(3))) u32*)l, 16, 0, 0);
}

// ---------------------------------------------------------------------------
// Weight prep (unchanged)
// ---------------------------------------------------------------------------
__global__ __launch_bounds__(256) void prep_weights(
    const float* __restrict__ qkv_w, const float* __restrict__ proj_w,
    const float* __restrict__ fc1_w, const float* __restrict__ fc2_w,
    const float* __restrict__ dw_w,
    u16* __restrict__ qkvt, u16* __restrict__ projt, u16* __restrict__ fc1t,
    u16* __restrict__ fc2t, float* __restrict__ dwtf)
{
    int id = blockIdx.x * 256 + threadIdx.x;
    if (id < 110592)      { int n = id / 192, k = id % 192;                 qkvt[id] = f2b(qkv_w[k * 576 + n]); }
    else if (id < 147456) { int e = id - 110592, n = e / 192, k = e % 192;  projt[e] = f2b(proj_w[k * 192 + n]); }
    else if (id < 294912) { int e = id - 147456, n = e / 192, k = e % 192;  fc1t[e]  = f2b(fc1_w[k * 768 + n]); }
    else if (id < 442368) { int e = id - 294912, n = e / 768, k = e % 768;  fc2t[e]  = f2b(fc2_w[k * 192 + n]); }
    else if (id < 463104) { int e = id - 442368, t = e / 768, c = e % 768;  dwtf[e]  = dw_w[c * 27 + t]; }
}

// ---------------------------------------------------------------------------
// Relative-position bias matrix, PADDED: bmat[head][112][112] f32 (unchanged)
// ---------------------------------------------------------------------------
__global__ __launch_bounds__(256) void biasmat_kernel(
    const float* __restrict__ btab, float* __restrict__ bmat)
{
    int id = blockIdx.x * 256 + threadIdx.x;
    if (id >= 6 * 112 * 112) return;
    int h = id / 12544, rem = id % 12544, i = rem / 112, j = rem % 112;
    float v;
    if (j >= 98)      v = -1e30f;
    else if (i >= 98) v = 0.0f;
    else {
        int di = i / 49, hi = (i / 7) % 7, wi = i % 7;
        int dj = j / 49, hj = (j / 7) % 7, wj = j % 7;
        int idx = (di - dj + 1) * 169 + (hi - hj + 6) * 13 + (wi - wj + 6);
        v = btab[idx * 6 + h];
    }
    bmat[id] = v;
}

// ---------------------------------------------------------------------------
// LayerNorm (unchanged)
// ---------------------------------------------------------------------------
template<bool PERM, bool BF_IN>
__global__ __launch_bounds__(256) void ln_kernel(
    const void* __restrict__ xin, const float* __restrict__ g,
    const float* __restrict__ bb, u16* __restrict__ out)
{
    int row  = blockIdx.x * 4 + (threadIdx.x >> 6);
    int lane = threadIdx.x & 63;
    float v0, v1, v2;
    if (BF_IN) {
        const u16* xr = (const u16*)xin + (size_t)row * DIMC;
        v0 = b2f(xr[lane]); v1 = b2f(xr[lane + 64]); v2 = b2f(xr[lane + 128]);
    } else {
        const float* xr = (const float*)xin + (size_t)row * DIMC;
        v0 = xr[lane]; v1 = xr[lane + 64]; v2 = xr[lane + 128];
    }
    float s  = v0 + v1 + v2;
    float s2 = v0 * v0 + v1 * v1 + v2 * v2;
    #pragma unroll
    for (int m = 1; m < 64; m <<= 1) { s += __shfl_xor(s, m); s2 += __shfl_xor(s2, m); }
    float mu = s * (1.0f / 192.0f);
    float rs = rsqrtf(s2 * (1.0f / 192.0f) - mu * mu + 1e-5f);
    size_t ob;
    if (PERM) {
        int b = row / 50176, r = row % 50176;
        int d = r / 3136, r2 = r % 3136, h = r2 / 56, w = r2 % 56;
        int widx = ((b * 8 + (d >> 1)) * 8 + h / 7) * 8 + w / 7;
        int tok  = (d & 1) * 49 + (h % 7) * 7 + (w % 7);
        ob = ((size_t)widx * 98 + tok) * DIMC;
    } else {
        ob = (size_t)row * DIMC;
    }
    out[ob + lane]       = f2b((v0 - mu) * rs * g[lane]       + bb[lane]);
    out[ob + lane + 64]  = f2b((v1 - mu) * rs * g[lane + 64]  + bb[lane + 64]);
    out[ob + lane + 128] = f2b((v2 - mu) * rs * g[lane + 128] + bb[lane + 128]);
}

// ---------------------------------------------------------------------------
// bf16 MFMA GEMM, BK=64 (kept from round 9 — verified, rest-time neutral+)
// ---------------------------------------------------------------------------
template<int EPI>
__global__ __launch_bounds__(256) void gemm_bt(
    const u16* __restrict__ A, const u16* __restrict__ Bt,
    const float* __restrict__ bias, int K, int N, int NBN,
    u16* __restrict__ outb, const float* __restrict__ xres,
    u16* __restrict__ x2b, float* __restrict__ outf, int mofs)
{
    __shared__ __align__(16) u16 Alds[2 * 128 * 32];
    __shared__ __align__(16) u16 Blds[2 * 64 * 32];
    int bid = blockIdx.x;
    int cpx = gridDim.x >> 3;
    int swz = (bid & 7) * cpx + (bid >> 3);
    int m0 = (swz / NBN) * 128;
    int n0 = (swz % NBN) * 64;
    int t  = threadIdx.x;
    int lane = t & 63, wid = t >> 6;
    int wm = wid >> 1, wn = wid & 1;
    int lrow = lane & 15, lko = (lane >> 4) * 8;
    int sr = t >> 2, sc = (t & 3) * 8;
    const u16* Ag = A  + (size_t)(m0 + sr) * K + sc;
    const u16* Bg = Bt + (size_t)(n0 + sr) * K + sc;
    u16* lA = Alds + t * 8;
    u16* lB = Blds + t * 8;
    f32x4 acc[4][2] = {};
    for (int kt = 0; kt < K; kt += 64) {
        __syncthreads();
        g2l16(Ag + kt,                       lA);
        g2l16(Ag + (size_t)64 * K + kt,      lA + 2048);
        g2l16(Ag + kt + 32,                  lA + 4096);
        g2l16(Ag + (size_t)64 * K + kt + 32, lA + 6144);
        g2l16(Bg + kt,      lB);
        g2l16(Bg + kt + 32, lB + 2048);
        __syncthreads();
        #pragma unroll
        for (int kk = 0; kk < 2; ++kk) {
            bf16x8 af[4], bfr[2];
            #pragma unroll
            for (int mi = 0; mi < 4; mi++)
                af[mi] = *(const bf16x8*)&Alds[kk * 4096 + (wm * 64 + mi * 16 + lrow) * 32 + lko];
            #pragma unroll
            for (int ni = 0; ni < 2; ni++)
                bfr[ni] = *(const bf16x8*)&Blds[kk * 2048 + (wn * 32 + ni * 16 + lrow) * 32 + lko];
            #pragma unroll
            for (int mi = 0; mi < 4; mi++)
                #pragma unroll
                for (int ni = 0; ni < 2; ni++)
                    acc[mi][ni] = __builtin_amdgcn_mfma_f32_16x16x32_bf16(af[mi], bfr[ni], acc[mi][ni], 0, 0, 0);
        }
    }
    int r0 = (lane >> 4) * 4, cl = lane & 15;
    #pragma unroll
    for (int ni = 0; ni < 2; ni++) {
        int col = n0 + wn * 32 + ni * 16 + cl;
        float bv = bias[col];
        #pragma unroll
        for (int mi = 0; mi < 4; mi++) {
            #pragma unroll
            for (int r = 0; r < 4; r++) {
                int row = m0 + wm * 64 + mi * 16 + r0 + r;
                float v = acc[mi][ni][r] + bv;
                if (EPI == 0) {
                    outb[(size_t)row * N + col] = f2b(v);
                } else if (EPI == 1) {
                    int widx = row / 98, tok = row % 98;
                    int b = widx >> 9, rem = widx & 511;
                    int bd = rem >> 6, bh = (rem >> 3) & 7, bw = rem & 7;
                    int td = tok / 49, rr = tok % 49, th = rr / 7, tw = rr % 7;
                    int d = bd * 2 + td, h = bh * 7 + th, w = bw * 7 + tw;
                    size_t gg = ((size_t)b * 50176 + (d * 56 + h) * 56 + w) * (size_t)N + col;
                    x2b[gg] = f2b(xres[gg] + 0.5f * v);
                } else {
                    size_t gg = (size_t)(row + mofs) * N + col;
                    outf[gg] = b2f(x2b[gg]) + 0.5f * v;
                }
            }
        }
    }
}

// ---------------------------------------------------------------------------
// MFMA window attention (unchanged)
// ---------------------------------------------------------------------------
__global__ __launch_bounds__(64) void attn_mfma_kernel(
    const u16* __restrict__ qkv, const float* __restrict__ bmat,
    u16* __restrict__ outb)
{
    __shared__ __align__(16) u16 Klds[112 * 40];
    __shared__ __align__(16) u16 Vt[32 * 136];
    __shared__ __align__(16) u16 Plds[16 * 136];
    int widx = blockIdx.x, head = blockIdx.y;
    int l = threadIdx.x;
    int c = l & 15, g = l >> 4;
    size_t wbase = (size_t)widx * (98 * 576) + head * 32;

    for (int e = l; e < 448; e += 64) {
        int rr = e >> 2, seg = (e & 3) * 8;
        uint4 kr = {0, 0, 0, 0}, vr = {0, 0, 0, 0};
        if (rr < 98) {
            kr = *(const uint4*)(qkv + wbase + (size_t)rr * 576 + 192 + seg);
            vr = *(const uint4*)(qkv + wbase + (size_t)rr * 576 + 384 + seg);
        }
        *(uint4*)&Klds[rr * 40 + seg] = kr;
        int sw = ((seg >> 3) & 3) << 4;
        int pc = rr ^ sw;
        const u16* vp = (const u16*)&vr;
        #pragma unroll
        for (int u = 0; u < 8; u++)
            Vt[(seg + u) * 136 + pc] = vp[u];
    }
    {
        int d = l >> 1, half = l & 1;
        int sw = ((d >> 3) & 3) << 4;
        uint4 z = {0, 0, 0, 0};
        *(uint4*)&Vt[d * 136 + ((112 + 8 * half) ^ sw)] = z;
        if (l < 32) {
            int i = l >> 1; half = l & 1;
            int swp = ((i >> 2) & 3) << 4;
            *(uint4*)&Plds[i * 136 + ((112 + 8 * half) ^ swp)] = z;
        }
    }

    for (int it = 0; it < 7; ++it) {
        int qtok = 16 * it + c; if (qtok > 97) qtok = 97;
        bf16x8 qf = *(const bf16x8*)(qkv + wbase + (size_t)qtok * 576 + g * 8);
        f32x4 s[7];
        f32x4 z = {};
        #pragma unroll
        for (int jt = 0; jt < 7; ++jt) {
            bf16x8 kf = *(const bf16x8*)&Klds[(16 * jt + c) * 40 + g * 8];
            s[jt] = __builtin_amdgcn_mfma_f32_16x16x32_bf16(qf, kf, z, 0, 0, 0);
        }
        const float* bb = bmat + ((size_t)head * 112 + 16 * it + 4 * g) * 112 + c;
        float sm[4];
        #pragma unroll
        for (int r = 0; r < 4; ++r) {
            float m = -1e30f;
            #pragma unroll
            for (int jt = 0; jt < 7; ++jt) {
                float v = s[jt][r] * SCALE_F + bb[r * 112 + 16 * jt];
                s[jt][r] = v;
                m = fmaxf(m, v);
            }
            m = fmaxf(m, __shfl_xor(m, 1)); m = fmaxf(m, __shfl_xor(m, 2));
            m = fmaxf(m, __shfl_xor(m, 4)); m = fmaxf(m, __shfl_xor(m, 8));
            float su = 0.f;
            #pragma unroll
            for (int jt = 0; jt < 7; ++jt) {
                float p = __expf(s[jt][r] - m);
                s[jt][r] = p;
                su += p;
            }
            su += __shfl_xor(su, 1); su += __shfl_xor(su, 2);
            su += __shfl_xor(su, 4); su += __shfl_xor(su, 8);
            sm[r] = su;
        }
        #pragma unroll
        for (int r = 0; r < 4; ++r) {
            int prow = 4 * g + r;
            int swp = ((prow >> 2) & 3) << 4;
            #pragma unroll
            for (int jt = 0; jt < 7; ++jt)
                Plds[prow * 136 + ((16 * jt + c) ^ swp)] = f2b(s[jt][r]);
        }
        bf16x8 pa[4];
        int swr = ((c >> 2) & 3) << 4;
        #pragma unroll
        for (int ks = 0; ks < 4; ++ks)
            pa[ks] = *(const bf16x8*)&Plds[c * 136 + ((32 * ks + 8 * g) ^ swr)];
        #pragma unroll
        for (int dt = 0; dt < 2; ++dt) {
            f32x4 o = {};
            int vrow = 16 * dt + c;
            int swv = ((vrow >> 3) & 3) << 4;
            #pragma unroll
            for (int ks = 0; ks < 4; ++ks) {
                bf16x8 vb = *(const bf16x8*)&Vt[vrow * 136 + ((32 * ks + 8 * g) ^ swv)];
                o = __builtin_amdgcn_mfma_f32_16x16x32_bf16(pa[ks], vb, o, 0, 0, 0);
            }
            #pragma unroll
            for (int r = 0; r < 4; ++r) {
                int row = 16 * it + 4 * g + r;
                if (row < 98)
                    outb[((size_t)widx * 98 + row) * DIMC + head * 32 + 16 * dt + c]
                        = f2b(o[r] / sm[r]);
            }
        }
    }
}

// ---------------------------------------------------------------------------
// Depthwise 3x3x3 conv + sigmoid-form GELU — EXACT round-8 kernel (proven
// 117 us/chunk, WRITE exactly-unique). Thread = 4 w-outputs x 4 channels,
// d-fastest mapping (16x192=3072 threads = 12 blocks, block-aligned chains)
// + XCD chunk swizzle.
// ---------------------------------------------------------------------------
__global__ __launch_bounds__(256, 8) void dwconv_gelu_kernel(
    const u16* __restrict__ hid, const float* __restrict__ dwtf,
    const float* __restrict__ dwb, u16* __restrict__ outb)
{
    int bid = blockIdx.x;
    int swz = (bid & 7) * 1176 + (bid >> 3);   // 9408 blocks / 8 XCDs
    int gid = swz * 256 + threadIdx.x;
    int cg = gid % 192;
    int t  = gid / 192;
    int d  = t & 15;
    t >>= 4;
    int wg = t % 14;
    int h  = t / 14;                  // 0..55
    int w0 = wg * 4;
    int c0 = cg * 4;

    f32x2 acc[4][2];
    {
        float4 bv = *(const float4*)(dwb + c0);
        #pragma unroll
        for (int wi = 0; wi < 4; ++wi) {
            acc[wi][0] = f32x2{bv.x, bv.y};
            acc[wi][1] = f32x2{bv.z, bv.w};
        }
    }

    #pragma unroll
    for (int iz = 0; iz < 3; ++iz) {
        int zz = d - 1 + iz;
        if ((unsigned)zz >= 16u) continue;
        #pragma unroll
        for (int iy = 0; iy < 3; ++iy) {
            int yy = h - 1 + iy;
            if ((unsigned)yy >= 56u) continue;
            uint2 raw[6];
            const u16* rp = hid + ((size_t)(zz * 56 + yy) * 56 + w0 - 1) * HIDC + c0;
            #pragma unroll
            for (int ix = 0; ix < 6; ++ix) {
                uint2 iv = {0, 0};
                if ((unsigned)(w0 - 1 + ix) < 56u)
                    iv = *(const uint2*)(rp + (size_t)ix * HIDC);
                raw[ix] = iv;
            }
            const float* wrow = dwtf + (size_t)(iz * 9 + iy * 3) * HIDC + c0;
            float4 wv0 = *(const float4*)(wrow);
            float4 wv1 = *(const float4*)(wrow + HIDC);
            float4 wv2 = *(const float4*)(wrow + 2 * HIDC);
            f32x2 wp[3][2] = {
                { f32x2{wv0.x, wv0.y}, f32x2{wv0.z, wv0.w} },
                { f32x2{wv1.x, wv1.y}, f32x2{wv1.z, wv1.w} },
                { f32x2{wv2.x, wv2.y}, f32x2{wv2.z, wv2.w} } };
            #pragma unroll
            for (int p = 0; p < 6; ++p) {
                f32x2 i0 = f32x2{lo2f(raw[p].x), hi2f(raw[p].x)};
                f32x2 i1 = f32x2{lo2f(raw[p].y), hi2f(raw[p].y)};
                #pragma unroll
                for (int dx = 0; dx < 3; ++dx) {
                    if (dx > p || dx < p - 3) continue;
                    acc[p - dx][0] += i0 * wp[dx][0];
                    acc[p - dx][1] += i1 * wp[dx][1];
                }
            }
        }
    }

    size_t tok0 = (size_t)(d * 56 + h) * 56 + w0;
    #pragma unroll
    for (int wi = 0; wi < 4; ++wi) {
        u16 res[4];
        #pragma unroll
        for (int pr = 0; pr < 2; ++pr)
            #pragma unroll
            for (int u = 0; u < 2; ++u) {
                float a = acc[wi][pr][u];
                float tt = a * (1.5957691216f + 0.0713548162f * a * a);
                res[pr * 2 + u] = f2b(a / (1.0f + __expf(-tt)));
            }
        uint2 ov;
        ov.x = (u32)res[0] | ((u32)res[1] << 16);
        ov.y = (u32)res[2] | ((u32)res[3] << 16);
        *(uint2*)(outb + (tok0 + wi) * HIDC + c0) = ov;
    }
}

// ---------------------------------------------------------------------------
// Orchestration (workspace layout unchanged).
// ---------------------------------------------------------------------------
extern "C" void kernel_launch(void* const* d_in, const int* in_sizes, int n_in,
                              void* d_out, int out_size, void* d_ws, size_t ws_size,
                              hipStream_t stream)
{
    const float* x      = (const float*)d_in[0];
    const float* n1g    = (const float*)d_in[1];
    const float* n1b    = (const float*)d_in[2];
    const float* qkv_w  = (const float*)d_in[3];
    const float* qkv_b  = (const float*)d_in[4];
    const float* btab   = (const float*)d_in[5];
    const float* proj_w = (const float*)d_in[6];
    const float* proj_b = (const float*)d_in[7];
    const float* n2g    = (const float*)d_in[8];
    const float* n2b    = (const float*)d_in[9];
    const float* fc1_w  = (const float*)d_in[10];
    const float* fc1_b  = (const float*)d_in[11];
    const float* dw_w   = (const float*)d_in[12];
    const float* dw_b   = (const float*)d_in[13];
    const float* fc2_w  = (const float*)d_in[14];
    const float* fc2_b  = (const float*)d_in[15];

    char* ws = (char*)d_ws;
    u16*   qkvt  = (u16*)(ws);
    u16*   projt = (u16*)(ws + 221184);
    u16*   fc1t  = (u16*)(ws + 294912);
    u16*   fc2t  = (u16*)(ws + 589824);
    float* dwtf  = (float*)(ws + 884736);
    u16*   r1    = (u16*)(ws + 1160192);
    u16*   qkvb  = (u16*)(ws + 39695360LL);
    u16*   x2b   = (u16*)(ws + 39695360LL);
    u16*   hid_c = (u16*)(ws + 78230528LL);
    float* bmat  = (float*)(ws + 155300864LL);
    u16*   gelu_c= (u16*)(ws + 155300864LL);

    prep_weights<<<dim3(1809), dim3(256), 0, stream>>>(qkv_w, proj_w, fc1_w, fc2_w, dw_w,
                                                       qkvt, projt, fc1t, fc2t, dwtf);
    biasmat_kernel<<<dim3(294), dim3(256), 0, stream>>>(btab, bmat);
    ln_kernel<true, false><<<dim3(25088), dim3(256), 0, stream>>>(x, n1g, n1b, r1);
    gemm_bt<0><<<dim3(7056), dim3(256), 0, stream>>>(r1, qkvt, qkv_b, 192, 576, 9,
                                                     qkvb, nullptr, nullptr, nullptr, 0);
    attn_mfma_kernel<<<dim3(1024, 6), dim3(64), 0, stream>>>(qkvb, bmat, r1);
    gemm_bt<1><<<dim3(2352), dim3(256), 0, stream>>>(r1, projt, proj_b, 192, 192, 3,
                                                     nullptr, x, x2b, nullptr, 0);
    ln_kernel<false, true><<<dim3(25088), dim3(256), 0, stream>>>(x2b, n2g, n2b, r1);
    for (int b = 0; b < 2; b++) {
        const u16* h2c = r1 + (size_t)b * M_HALF * DIMC;
        gemm_bt<0><<<dim3(4704), dim3(256), 0, stream>>>(h2c, fc1t, fc1_b, 192, 768, 12,
                                                         hid_c, nullptr, nullptr, nullptr, 0);
        dwconv_gelu_kernel<<<dim3(9408), dim3(256), 0, stream>>>(hid_c, dwtf, dw_b, gelu_c);
        gemm_bt<2><<<dim3(1176), dim3(256), 0, stream>>>(gelu_c, fc2t, fc2_b, 768, 192, 3,
                                                         nullptr, nullptr, x2b, (float*)d_out,
                                                         b * M_HALF);
    }
}